// Round 1
// baseline (2524.595 us; speedup 1.0000x reference)
//
#include <hip/hip_runtime.h>

#define N_NODES 50000
#define N_EDGES 400000
#define EPSV 1e-5f

// ---------------- encoders: out = relu(in2 @ W1 + b1) @ W2 + b2 ----------------
__global__ __launch_bounds__(256) void encode_kernel(
    const float* __restrict__ in2, const float* __restrict__ W1,
    const float* __restrict__ b1, const float* __restrict__ W2,
    const float* __restrict__ b2, float* __restrict__ out, int nrows)
{
  int t = blockIdx.x * 256 + threadIdx.x;
  int row = t >> 4;
  int d0 = t & 15;
  if (row >= nrows) return;
  float x0 = in2[row * 2 + 0], x1 = in2[row * 2 + 1];
  float h[16];
#pragma unroll
  for (int j = 0; j < 16; ++j)
    h[j] = fmaxf(fmaf(x0, W1[j], fmaf(x1, W1[16 + j], b1[j])), 0.f);
#pragma unroll
  for (int q = 0; q < 4; ++q) {
    int d = d0 + q * 16;
    float a = b2[d];
#pragma unroll
    for (int j = 0; j < 16; ++j) a = fmaf(h[j], W2[j * 64 + d], a);
    out[(size_t)row * 64 + d] = a;
  }
}

// ---------------- CSR build ----------------
__global__ __launch_bounds__(256) void hist_kernel(
    const int* __restrict__ src, const int* __restrict__ dst,
    int* __restrict__ cnt_f, int* __restrict__ cnt_b)
{
  int t = blockIdx.x * 256 + threadIdx.x;
  if (t >= N_EDGES) return;
  atomicAdd(&cnt_f[dst[t]], 1);
  atomicAdd(&cnt_b[src[t]], 1);
}

__global__ __launch_bounds__(1024) void scan_kernel(
    const int* __restrict__ cnt_f, const int* __restrict__ cnt_b,
    int* __restrict__ off_f, int* __restrict__ off_b,
    int* __restrict__ cur_f, int* __restrict__ cur_b)
{
  __shared__ int sh[1024];
  const int n = N_NODES;
  const int SEG = (n + 1023) / 1024;
  const int* cnt = blockIdx.x ? cnt_b : cnt_f;
  int* off = blockIdx.x ? off_b : off_f;
  int* cur = blockIdx.x ? cur_b : cur_f;
  int t = threadIdx.x;
  int base = t * SEG;
  int s = 0;
  for (int i = 0; i < SEG; ++i) {
    int idx = base + i;
    if (idx < n) s += cnt[idx];
  }
  sh[t] = s;
  __syncthreads();
  for (int o = 1; o < 1024; o <<= 1) {
    int v = sh[t];
    int u = (t >= o) ? sh[t - o] : 0;
    __syncthreads();
    sh[t] = v + u;
    __syncthreads();
  }
  int run = (t > 0) ? sh[t - 1] : 0;
  for (int i = 0; i < SEG; ++i) {
    int idx = base + i;
    if (idx < n) {
      off[idx] = run;
      cur[idx] = run;
      run += cnt[idx];
    }
  }
  if (t == 1023) off[n] = sh[1023];
}

__global__ __launch_bounds__(256) void fill_kernel(
    const int* __restrict__ src, const int* __restrict__ dst,
    int* __restrict__ cur_f, int* __restrict__ cur_b,
    int2* __restrict__ csr_f, int2* __restrict__ csr_b)
{
  int t = blockIdx.x * 256 + threadIdx.x;
  if (t >= N_EDGES) return;
  int dv = dst[t], sv = src[t];
  int p = atomicAdd(&cur_f[dv], 1);
  csr_f[p] = make_int2(t, sv);
  int q = atomicAdd(&cur_b[sv], 1);
  csr_b[q] = make_int2(t, dv);
}

// deterministic order within each segment (atomic fill order is arbitrary)
__global__ __launch_bounds__(256) void sort_kernel(
    const int* __restrict__ off_f, const int* __restrict__ off_b,
    int2* __restrict__ csr_f, int2* __restrict__ csr_b)
{
  int t = blockIdx.x * 256 + threadIdx.x;
  int n;
  int2* csr;
  const int* off;
  if (t < N_NODES) { n = t; csr = csr_f; off = off_f; }
  else if (t < 2 * N_NODES) { n = t - N_NODES; csr = csr_b; off = off_b; }
  else return;
  int b = off[n], e = off[n + 1];
  for (int i = b + 1; i < e; ++i) {
    int2 key = csr[i];
    int j = i - 1;
    while (j >= b && csr[j].x > key.x) { csr[j + 1] = csr[j]; --j; }
    csr[j + 1] = key;
  }
}

// ---------------- node GEMMs: NA[m] = X @ W_m + b_m  (m: A1,A2,A3,B1,B2) -------
__global__ __launch_bounds__(64) void node_gemm_kernel(
    const float* __restrict__ X,
    const float* __restrict__ A1, const float* __restrict__ A2,
    const float* __restrict__ A3, const float* __restrict__ B1,
    const float* __restrict__ B2,
    const float* __restrict__ bA1, const float* __restrict__ bA2,
    const float* __restrict__ bA3, const float* __restrict__ bB1,
    const float* __restrict__ bB2,
    float* __restrict__ NA, int l)
{
  __shared__ float xin[64 * 65];
  __shared__ float outb[64 * 65];
  int w = blockIdx.x;
  int m = w % 5;
  int c = w / 5;
  int lane = threadIdx.x;
  int row0 = c * 64;
  for (int r = 0; r < 64; ++r) {
    int row = row0 + r;
    xin[r * 65 + lane] = (row < N_NODES) ? X[(size_t)row * 64 + lane] : 0.f;
  }
  __syncthreads();
  const float* W;
  const float* bb;
  if (m == 0) { W = A1; bb = bA1; }
  else if (m == 1) { W = A2; bb = bA2; }
  else if (m == 2) { W = A3; bb = bA3; }
  else if (m == 3) { W = B1; bb = bB1; }
  else { W = B2; bb = bB2; }
  W += l * 64 * 64;
  bb += l * 64;
  float acc[64];
#pragma unroll
  for (int d = 0; d < 64; ++d) acc[d] = bb[d];
#pragma unroll 2
  for (int k = 0; k < 64; ++k) {
    float xv = xin[lane * 65 + k];
#pragma unroll
    for (int d = 0; d < 64; ++d) acc[d] = fmaf(xv, W[k * 64 + d], acc[d]);
  }
#pragma unroll
  for (int d = 0; d < 64; ++d) outb[lane * 65 + d] = acc[d];
  __syncthreads();
  float* out = NA + (size_t)m * N_NODES * 64;
  for (int r = 0; r < 64; ++r) {
    int row = row0 + r;
    if (row < N_NODES) out[(size_t)row * 64 + lane] = outb[r * 65 + lane];
  }
}

// ---------------- edge update: e += relu(LN(b1x[src]+b2x[dst]+e@B3+bB3)) -------
__global__ __launch_bounds__(256) void edge_update_kernel(
    const float* __restrict__ NA,
    const float* __restrict__ B3, const float* __restrict__ bB3,
    const float* __restrict__ ge, const float* __restrict__ be,
    const int* __restrict__ src, const int* __restrict__ dst,
    float* __restrict__ E64, int l)
{
  __shared__ float buf[4 * 64 * 65];
  int wave = threadIdx.x >> 6;
  int lane = threadIdx.x & 63;
  int chunk = blockIdx.x * 4 + wave;
  float* lds = buf + wave * 64 * 65;
  bool active = (chunk * 64 < N_EDGES);
  int e0 = chunk * 64;
  if (active) {
    for (int r = 0; r < 64; ++r)
      lds[r * 65 + lane] = E64[(size_t)(e0 + r) * 64 + lane];
  }
  __syncthreads();
  if (active) {
    const float* W = B3 + l * 64 * 64;
    const float* b1x = NA + (size_t)3 * N_NODES * 64;
    const float* b2x = NA + (size_t)4 * N_NODES * 64;
    int sv = src[e0 + lane], dv = dst[e0 + lane];
    float acc[64];
#pragma unroll
    for (int d = 0; d < 64; ++d) acc[d] = bB3[l * 64 + d];
#pragma unroll 2
    for (int k = 0; k < 64; ++k) {
      float ev = lds[lane * 65 + k];
#pragma unroll
      for (int d = 0; d < 64; ++d) acc[d] = fmaf(ev, W[k * 64 + d], acc[d]);
    }
#pragma unroll
    for (int j = 0; j < 16; ++j) {
      float4 g1 = *reinterpret_cast<const float4*>(&b1x[(size_t)sv * 64 + j * 4]);
      float4 g2 = *reinterpret_cast<const float4*>(&b2x[(size_t)dv * 64 + j * 4]);
      acc[j * 4 + 0] += g1.x + g2.x;
      acc[j * 4 + 1] += g1.y + g2.y;
      acc[j * 4 + 2] += g1.z + g2.z;
      acc[j * 4 + 3] += g1.w + g2.w;
    }
    float s = 0.f;
#pragma unroll
    for (int d = 0; d < 64; ++d) s += acc[d];
    float mean = s * (1.f / 64.f);
    float s2 = 0.f;
#pragma unroll
    for (int d = 0; d < 64; ++d) {
      float dd = acc[d] - mean;
      s2 = fmaf(dd, dd, s2);
    }
    float rstd = rsqrtf(s2 * (1.f / 64.f) + EPSV);
#pragma unroll
    for (int d = 0; d < 64; ++d) {
      float ln = fmaf((acc[d] - mean) * rstd, ge[l * 64 + d], be[l * 64 + d]);
      float eo = lds[lane * 65 + d];
      lds[lane * 65 + d] = eo + fmaxf(ln, 0.f);
    }
  }
  __syncthreads();
  if (active) {
    for (int r = 0; r < 64; ++r)
      E64[(size_t)(e0 + r) * 64 + lane] = lds[r * 65 + lane];
  }
}

// ---------------- gated aggregation + node update ----------------
__global__ __launch_bounds__(256) void aggregate_kernel(
    const float* __restrict__ NA, const float* __restrict__ E64,
    const int* __restrict__ off_f, const int* __restrict__ off_b,
    const int2* __restrict__ csr_f, const int2* __restrict__ csr_b,
    const float* __restrict__ gh, const float* __restrict__ bh,
    float* __restrict__ X, int l)
{
  int wave = threadIdx.x >> 6;
  int lane = threadIdx.x & 63;
  int n = blockIdx.x * 4 + wave;
  if (n >= N_NODES) return;
  const float* A1x = NA;
  const float* A2x = NA + (size_t)N_NODES * 64;
  const float* A3x = NA + (size_t)2 * N_NODES * 64;
  float mf = 0.f, df = 0.f, mb = 0.f, db = 0.f;
  int p0 = off_f[n], p1 = off_f[n + 1];
  for (int p = p0; p < p1; ++p) {
    int2 pr = csr_f[p];
    float ev = E64[(size_t)pr.x * 64 + lane];
    float sg = 1.f / (1.f + __expf(-ev));
    mf = fmaf(sg, A2x[(size_t)pr.y * 64 + lane], mf);
    df += sg;
  }
  p0 = off_b[n];
  p1 = off_b[n + 1];
  for (int p = p0; p < p1; ++p) {
    int2 pr = csr_b[p];
    float ev = E64[(size_t)pr.x * 64 + lane];
    float sg = 1.f / (1.f + __expf(-ev));
    mb = fmaf(sg, A3x[(size_t)pr.y * 64 + lane], mb);
    db += sg;
  }
  float h = A1x[(size_t)n * 64 + lane] + mf / (df + EPSV) + mb / (db + EPSV);
  float s1 = h;
#pragma unroll
  for (int m = 1; m < 64; m <<= 1) s1 += __shfl_xor(s1, m, 64);
  float mean = s1 * (1.f / 64.f);
  float dd = h - mean;
  float s2 = dd * dd;
#pragma unroll
  for (int m = 1; m < 64; m <<= 1) s2 += __shfl_xor(s2, m, 64);
  float rstd = rsqrtf(s2 * (1.f / 64.f) + EPSV);
  float xo = X[(size_t)n * 64 + lane];
  X[(size_t)n * 64 + lane] =
      xo + fmaxf(fmaf(dd * rstd, gh[l * 64 + lane], bh[l * 64 + lane]), 0.f);
}

// ---------------- predictor: relu(cat(x[src],x[dst],e) @ pW1 + pb1) @ pW2 + pb2
__global__ __launch_bounds__(256) void predictor_kernel(
    const float* __restrict__ X, const float* __restrict__ E64,
    const int* __restrict__ src, const int* __restrict__ dst,
    const float* __restrict__ pW1, const float* __restrict__ pb1,
    const float* __restrict__ pW2, const float* __restrict__ pb2,
    float* __restrict__ out)
{
  __shared__ float buf[4 * 64 * 65];
  int wave = threadIdx.x >> 6;
  int lane = threadIdx.x & 63;
  int chunk = blockIdx.x * 4 + wave;
  float* lds = buf + wave * 64 * 65;
  bool active = (chunk * 64 < N_EDGES);
  int e0 = chunk * 64;
  if (active) {
    for (int r = 0; r < 64; ++r)
      lds[r * 65 + lane] = E64[(size_t)(e0 + r) * 64 + lane];
  }
  __syncthreads();
  if (!active) return;
  int sv = src[e0 + lane], dv = dst[e0 + lane];
  float acc[64];
#pragma unroll
  for (int d = 0; d < 64; ++d) acc[d] = pb1[d];
#pragma unroll 2
  for (int k = 0; k < 64; ++k) {
    float ev = lds[lane * 65 + k];
#pragma unroll
    for (int d = 0; d < 64; ++d) acc[d] = fmaf(ev, pW1[(128 + k) * 64 + d], acc[d]);
  }
#pragma unroll 2
  for (int j = 0; j < 16; ++j) {
    float4 xv = *reinterpret_cast<const float4*>(&X[(size_t)sv * 64 + j * 4]);
    float vv[4] = {xv.x, xv.y, xv.z, xv.w};
#pragma unroll
    for (int kk = 0; kk < 4; ++kk)
#pragma unroll
      for (int d = 0; d < 64; ++d)
        acc[d] = fmaf(vv[kk], pW1[(j * 4 + kk) * 64 + d], acc[d]);
  }
#pragma unroll 2
  for (int j = 0; j < 16; ++j) {
    float4 xv = *reinterpret_cast<const float4*>(&X[(size_t)dv * 64 + j * 4]);
    float vv[4] = {xv.x, xv.y, xv.z, xv.w};
#pragma unroll
    for (int kk = 0; kk < 4; ++kk)
#pragma unroll
      for (int d = 0; d < 64; ++d)
        acc[d] = fmaf(vv[kk], pW1[(64 + j * 4 + kk) * 64 + d], acc[d]);
  }
  float o = pb2[0];
#pragma unroll
  for (int d = 0; d < 64; ++d) o = fmaf(fmaxf(acc[d], 0.f), pW2[d], o);
  out[e0 + lane] = o;
}

extern "C" void kernel_launch(void* const* d_in, const int* in_sizes, int n_in,
                              void* d_out, int out_size, void* d_ws, size_t ws_size,
                              hipStream_t stream)
{
  const float* x = (const float*)d_in[0];
  const float* e = (const float*)d_in[1];
  const int* src = (const int*)d_in[2];
  const int* dst = (const int*)d_in[3];
  const float* neW1 = (const float*)d_in[4];
  const float* neb1 = (const float*)d_in[5];
  const float* neW2 = (const float*)d_in[6];
  const float* neb2 = (const float*)d_in[7];
  const float* eeW1 = (const float*)d_in[8];
  const float* eeb1 = (const float*)d_in[9];
  const float* eeW2 = (const float*)d_in[10];
  const float* eeb2 = (const float*)d_in[11];
  const float* A1 = (const float*)d_in[12];
  const float* bA1 = (const float*)d_in[13];
  const float* A2 = (const float*)d_in[14];
  const float* bA2 = (const float*)d_in[15];
  const float* A3 = (const float*)d_in[16];
  const float* bA3 = (const float*)d_in[17];
  const float* B1 = (const float*)d_in[18];
  const float* bB1 = (const float*)d_in[19];
  const float* B2 = (const float*)d_in[20];
  const float* bB2 = (const float*)d_in[21];
  const float* B3 = (const float*)d_in[22];
  const float* bB3 = (const float*)d_in[23];
  const float* ge = (const float*)d_in[24];
  const float* be = (const float*)d_in[25];
  const float* gh = (const float*)d_in[26];
  const float* bh = (const float*)d_in[27];
  const float* pW1 = (const float*)d_in[28];
  const float* pb1 = (const float*)d_in[29];
  const float* pW2 = (const float*)d_in[30];
  const float* pb2 = (const float*)d_in[31];

  char* ws = (char*)d_ws;
  float* X = (float*)ws;      ws += (size_t)N_NODES * 64 * 4;
  float* NA = (float*)ws;     ws += (size_t)5 * N_NODES * 64 * 4;
  float* E64 = (float*)ws;    ws += (size_t)N_EDGES * 64 * 4;
  int* cnt_f = (int*)ws;      ws += (size_t)N_NODES * 4;
  int* cnt_b = (int*)ws;      ws += (size_t)N_NODES * 4;
  int* off_f = (int*)ws;      ws += (size_t)(N_NODES + 1) * 4;
  int* off_b = (int*)ws;      ws += (size_t)(N_NODES + 1) * 4;
  int* cur_f = (int*)ws;      ws += (size_t)N_NODES * 4;
  int* cur_b = (int*)ws;      ws += (size_t)N_NODES * 4;
  int2* csr_f = (int2*)ws;    ws += (size_t)N_EDGES * 8;
  int2* csr_b = (int2*)ws;    ws += (size_t)N_EDGES * 8;

  // encoders
  encode_kernel<<<(N_NODES * 16 + 255) / 256, 256, 0, stream>>>(
      x, neW1, neb1, neW2, neb2, X, N_NODES);
  encode_kernel<<<(N_EDGES * 16 + 255) / 256, 256, 0, stream>>>(
      e, eeW1, eeb1, eeW2, eeb2, E64, N_EDGES);

  // CSR build (deterministic after sort)
  hipMemsetAsync(cnt_f, 0, (size_t)2 * N_NODES * 4, stream);
  hist_kernel<<<(N_EDGES + 255) / 256, 256, 0, stream>>>(src, dst, cnt_f, cnt_b);
  scan_kernel<<<2, 1024, 0, stream>>>(cnt_f, cnt_b, off_f, off_b, cur_f, cur_b);
  fill_kernel<<<(N_EDGES + 255) / 256, 256, 0, stream>>>(src, dst, cur_f, cur_b,
                                                         csr_f, csr_b);
  sort_kernel<<<(2 * N_NODES + 255) / 256, 256, 0, stream>>>(off_f, off_b, csr_f,
                                                             csr_b);

  // layers
  for (int l = 0; l < 4; ++l) {
    node_gemm_kernel<<<782 * 5, 64, 0, stream>>>(X, A1, A2, A3, B1, B2, bA1, bA2,
                                                 bA3, bB1, bB2, NA, l);
    edge_update_kernel<<<1563, 256, 0, stream>>>(NA, B3, bB3, ge, be, src, dst,
                                                 E64, l);
    aggregate_kernel<<<(N_NODES + 3) / 4, 256, 0, stream>>>(
        NA, E64, off_f, off_b, csr_f, csr_b, gh, bh, X, l);
  }

  // predictor
  predictor_kernel<<<1563, 256, 0, stream>>>(X, E64, src, dst, pW1, pb1, pW2, pb2,
                                             (float*)d_out);
}